// Round 12
// baseline (371.866 us; speedup 1.0000x reference)
//
#include <hip/hip_runtime.h>

// ---------------- Problem constants ----------------
#define BATCH 16
#define TSEQ  4096
#define HDIM  512
#define NDIM  512
#define NCHUNK 64
#define LCHUNK 64   // TSEQ / NCHUNK

using f32x4  = __attribute__((ext_vector_type(4))) float;
using bf16x8 = __attribute__((ext_vector_type(8))) short;

typedef const __attribute__((address_space(1))) void GV;
typedef __attribute__((address_space(3))) void LV;

__device__ __forceinline__ void gload16(const void* g, void* l) {
  __builtin_amdgcn_global_load_lds((GV*)g, (LV*)l, 16, 0, 0);
}
__device__ __forceinline__ unsigned short f2bf(float f) {
  unsigned u = __float_as_uint(f);
  return (unsigned short)((u + 0x7fffu + ((u >> 16) & 1u)) >> 16);
}
__device__ __forceinline__ float bf2f(unsigned short s) {
  return __uint_as_float(((unsigned)s) << 16);
}

// ---------------- Param prep ----------------
__global__ void prep_params(const float* __restrict__ nu_log,
                            const float* __restrict__ theta_log,
                            float* lam_re, float* lam_im, float* gam,
                            float* lamL_re, float* lamL_im) {
  int n = threadIdx.x;
  float en = expf(nu_log[n]);
  float th = expf(theta_log[n]);
  float r  = expf(-en);
  lam_re[n] = r * cosf(th);
  lam_im[n] = r * sinf(th);
  float r2 = expf(-2.f * en);
  gam[n] = sqrtf(fmaxf(1.f - r2, 0.f));
  float rL  = expf(-(float)LCHUNK * en);
  float thL = (float)LCHUNK * th;
  lamL_re[n] = rL * cosf(thL);
  lamL_im[n] = rL * sinf(thL);
}

__global__ void prep_bcat(const float* __restrict__ B_re, const float* __restrict__ B_im,
                          const float* __restrict__ gam, unsigned short* __restrict__ Bcat) {
  int idx = blockIdx.x * 256 + threadIdx.x;
  int h   = idx & (HDIM - 1);
  int row = idx >> 9;
  int n   = row >> 1;
  float g = gam[n];
  float v = (row & 1) ? B_im[n * HDIM + h] : B_re[n * HDIM + h];
  Bcat[idx] = f2bf(g * v);
}

__global__ void prep_ccat(const float* __restrict__ C_re, const float* __restrict__ C_im,
                          unsigned short* __restrict__ Ccat) {
  int idx = blockIdx.x * 256 + threadIdx.x;
  int col = idx & (2 * NDIM - 1);
  int h   = idx >> 10;
  int n   = col >> 1;
  float v = (col & 1) ? -C_im[h * NDIM + n] : C_re[h * NDIM + n];
  Ccat[idx] = f2bf(v);
}

__global__ void conv_u(const float4* __restrict__ u, ushort4* __restrict__ ub, int n4) {
  int idx = blockIdx.x * 256 + threadIdx.x;
  if (idx >= n4) return;
  float4 v = u[idx];
  ushort4 o;
  o.x = f2bf(v.x); o.y = f2bf(v.y); o.z = f2bf(v.z); o.w = f2bf(v.w);
  ub[idx] = o;
}

// ---------------- 64x64 single-wave bf16 MFMA GEMM (barrier-free) ----------
// C[M,Nd] = A[M,K] @ Bm[Nd,K]^T.  OUTBF: write bf16 (GEMM1->Bu),
// else f32 out + D*u epilogue (GEMM2->outs).
// r11 post-mortem: all barrier-synced schedules (r3-r5, r7-r11) land 2.5-3x
// above pipe floors; stalls need CO-RESIDENT blocks to hide (m114), but
// occupancy never exceeded 3 blocks/CU. This kernel removes barriers
// entirely: ONE wave per block, private 16 KiB LDS slice (A 8K + B 8K),
// own-wave vmcnt(0) gates (no cross-wave hazard exists). 16 KiB x 10 blocks
// = 160 KiB/CU exactly; ~134 regs -> 10 independent waves/CU whose HBM/L2
// waits mutually overlap. DS-pipe ceiling ~9.4 tiles/us/CU >> measured 4.1.
//  - T2 XOR-swizzle byte ^= ((row&7)<<4) via pre-swizzled global source
//    (identical formulas to r7-r11, numerically proven).
//  - T1 XCD chunking, col-block fastest (B+A panels L2-resident per chunk).
template <int K, bool OUTBF>
__global__ __launch_bounds__(64, 3)
void gemmw(const unsigned short* __restrict__ A,
           const unsigned short* __restrict__ Bm,
           void* __restrict__ Co, int Ncol, int Nd,
           const unsigned short* __restrict__ ub,
           const float* __restrict__ Dv) {
  __shared__ char lds[16384];  // [A: 0..8191][B: 8192..16383], 64 rows x 128 B
  const int lane = threadIdx.x;

  // T1: XCD chunking (nwg % 8 == 0), col-block fastest within a chunk.
  int nwg = gridDim.x;
  int bid = blockIdx.x;
  int wg  = (bid & 7) * (nwg >> 3) + (bid >> 3);
  int bn = wg % Ncol, bm = wg / Ncol;
  const long rowBase = (long)bm * 64;
  const long colBase = (long)bn * 64;

  // Pre-swizzled global sources. Stage instr r writes LDS rows r*8..r*8+7:
  // lane -> row_local = r*8 + (lane>>3), colbyte = (lane&7)*16; source col
  // pre-XORed so linear LDS holds swizzled data. row_local&7 == lane>>3.
  const int colE = 8 * ((lane & 7) ^ (lane >> 3));
  const unsigned short* srcA = A  + (rowBase + (lane >> 3)) * (long)K + colE;
  const unsigned short* srcB = Bm + (colBase + (lane >> 3)) * (long)K + colE;

  f32x4 acc[4][4];
#pragma unroll
  for (int i = 0; i < 4; i++)
#pragma unroll
    for (int j = 0; j < 4; j++) acc[i][j] = (f32x4){0.f, 0.f, 0.f, 0.f};

  const int rsub = lane & 15;
  const int sx   = (lane & 7) << 4;   // row&7 == lane&7 for all fragment rows
  const int ke   = (lane >> 4) << 4;  // k-subgroup byte offset (8 elems)

  for (int kt = 0; kt < K; kt += 64) {
    // Stage this wave's A+B tile (16 KiB, 16 gload_lds). No barrier needed:
    // prior MFMAs already forced lgkm drain of last tile's ds_reads.
#pragma unroll
    for (int r = 0; r < 8; r++)
      gload16(srcA + kt + (long)r * 8 * K, &lds[r * 1024 + lane * 16]);
#pragma unroll
    for (int r = 0; r < 8; r++)
      gload16(srcB + kt + (long)r * 8 * K, &lds[8192 + r * 1024 + lane * 16]);
    asm volatile("s_waitcnt vmcnt(0)" ::: "memory");  // own loads only
#pragma unroll
    for (int kk2 = 0; kk2 < 2; kk2++) {
      bf16x8 af[4], bf[4];
#pragma unroll
      for (int i = 0; i < 4; i++) {
        int off = (((i * 16 + rsub) << 7) + kk2 * 64 + ke) ^ sx;
        af[i] = *(const bf16x8*)&lds[off];
      }
#pragma unroll
      for (int j = 0; j < 4; j++) {
        int off = 8192 + ((((j * 16 + rsub) << 7) + kk2 * 64 + ke) ^ sx);
        bf[j] = *(const bf16x8*)&lds[off];
      }
#pragma unroll
      for (int i = 0; i < 4; i++)
#pragma unroll
        for (int j = 0; j < 4; j++)
          acc[i][j] = __builtin_amdgcn_mfma_f32_16x16x32_bf16(af[i], bf[j], acc[i][j], 0, 0, 0);
    }
  }

  // Epilogue (proven mapping: col=lane&15, row=(lane>>4)*4+r)
  const int cc = lane & 15, r4 = (lane >> 4) * 4;
#pragma unroll
  for (int i = 0; i < 4; i++) {
#pragma unroll
    for (int j = 0; j < 4; j++) {
      long col = colBase + j * 16 + cc;
#pragma unroll
      for (int r = 0; r < 4; r++) {
        long row = rowBase + i * 16 + r4 + r;
        if (OUTBF) {
          ((unsigned short*)Co)[row * (long)Nd + col] = f2bf(acc[i][j][r]);
        } else {
          float d = Dv[col];
          ((float*)Co)[row * (long)Nd + col] =
              acc[i][j][r] + d * bf2f(ub[row * (long)Nd + col]);
        }
      }
    }
  }
}

// ---------------- Chunked complex scan (Bu packed bf16 re|im) ----------------
__global__ void scan_carry(const unsigned* __restrict__ Bu,
                           const float* __restrict__ lam_re, const float* __restrict__ lam_im,
                           float2* __restrict__ V) {
  int idx  = blockIdx.x * 256 + threadIdx.x;
  int n    = idx & (NDIM - 1);
  int c    = (idx >> 9) & (NCHUNK - 1);
  int bloc = idx >> 15;
  float lr = lam_re[n], li = lam_im[n];
  float xr = 0.f, xi = 0.f;
  long base = ((long)bloc * TSEQ + c * LCHUNK) * NDIM + n;
#pragma unroll 4
  for (int j = 0; j < LCHUNK; j++) {
    unsigned pv = Bu[base + (long)j * NDIM];
    float br = bf2f((unsigned short)(pv & 0xffff));
    float bi = bf2f((unsigned short)(pv >> 16));
    float nr = lr * xr - li * xi + br;
    float ni = lr * xi + li * xr + bi;
    xr = nr; xi = ni;
  }
  V[idx] = make_float2(xr, xi);
}

__global__ void scan_combine(const float2* __restrict__ V,
                             const float* __restrict__ lamL_re, const float* __restrict__ lamL_im,
                             const float* __restrict__ x0r, const float* __restrict__ x0i,
                             int b0, float2* __restrict__ In) {
  int idx  = blockIdx.x * 256 + threadIdx.x;
  int n    = idx & (NDIM - 1);
  int bloc = idx >> 9;
  int b    = b0 + bloc;
  float lr = lamL_re[n], li = lamL_im[n];
  float sr = x0r[b * NDIM + n], si = x0i[b * NDIM + n];
  long base = (long)bloc * NCHUNK * NDIM + n;
  for (int c = 0; c < NCHUNK; c++) {
    In[base + c * NDIM] = make_float2(sr, si);
    float2 v = V[base + c * NDIM];
    float nr = lr * sr - li * si + v.x;
    float ni = lr * si + li * sr + v.y;
    sr = nr; si = ni;
  }
}

__global__ void scan_apply(const unsigned* __restrict__ Bu, const float2* __restrict__ In,
                           const float* __restrict__ lam_re, const float* __restrict__ lam_im,
                           unsigned int* __restrict__ xsb, float* __restrict__ fs,
                           int b0, int fs_mode) {
  int idx  = blockIdx.x * 256 + threadIdx.x;
  int n    = idx & (NDIM - 1);
  int c    = (idx >> 9) & (NCHUNK - 1);
  int bloc = idx >> 15;
  float lr = lam_re[n], li = lam_im[n];
  float2 s = In[idx];
  float xr = s.x, xi = s.y;
  long base = ((long)bloc * TSEQ + c * LCHUNK) * NDIM + n;
#pragma unroll 4
  for (int j = 0; j < LCHUNK; j++) {
    unsigned pv = Bu[base + (long)j * NDIM];
    float br = bf2f((unsigned short)(pv & 0xffff));
    float bi = bf2f((unsigned short)(pv >> 16));
    float nr = lr * xr - li * xi + br;
    float ni = lr * xi + li * xr + bi;
    xr = nr; xi = ni;
    xsb[base + (long)j * NDIM] = (unsigned)f2bf(xr) | ((unsigned)f2bf(xi) << 16);
  }
  if (c == NCHUNK - 1 && fs_mode >= 0) {
    int b = b0 + bloc;
    if (fs_mode == 1) {
      fs[(size_t)(b * NDIM + n) * 2]     = xr;
      fs[(size_t)(b * NDIM + n) * 2 + 1] = xi;
    } else {
      fs[(size_t)(b * NDIM + n)] = xr;
    }
  }
}

// ---------------- Host launch ----------------
extern "C" void kernel_launch(void* const* d_in, const int* in_sizes, int n_in,
                              void* d_out, int out_size, void* d_ws, size_t ws_size,
                              hipStream_t stream) {
  const float* x0r       = (const float*)d_in[0];
  const float* x0i       = (const float*)d_in[1];
  const float* u         = (const float*)d_in[2];
  const float* nu_log    = (const float*)d_in[3];
  const float* theta_log = (const float*)d_in[4];
  const float* B_re      = (const float*)d_in[5];
  const float* B_im      = (const float*)d_in[6];
  const float* C_re      = (const float*)d_in[7];
  const float* C_im      = (const float*)d_in[8];
  const float* Dv        = (const float*)d_in[9];

  char* ws = (char*)d_ws;
  size_t off = 0;
  auto alloc = [&](size_t bytes) {
    char* p = ws + off;
    off = (off + bytes + 255) & ~(size_t)255;
    return p;
  };

  float* lam_re  = (float*)alloc(NDIM * 4);
  float* lam_im  = (float*)alloc(NDIM * 4);
  float* gam     = (float*)alloc(NDIM * 4);
  float* lamL_re = (float*)alloc(NDIM * 4);
  float* lamL_im = (float*)alloc(NDIM * 4);
  unsigned short* Bcat = (unsigned short*)alloc((size_t)2 * NDIM * HDIM * 2);
  unsigned short* Ccat = (unsigned short*)alloc((size_t)HDIM * 2 * NDIM * 2);

  const size_t per_batch =
      (size_t)TSEQ * HDIM * 2 +       // u bf16
      (size_t)TSEQ * NDIM * 4 +       // Bu packed bf16 (re|im)
      (size_t)TSEQ * NDIM * 4 +       // xs packed bf16
      (size_t)2 * NCHUNK * NDIM * 8 + // V, In
      4096;
  int G = 16;
  while (G > 1 && off + (size_t)G * per_batch > ws_size) G >>= 1;

  ushort4*      ub  = (ushort4*)alloc((size_t)G * TSEQ * HDIM * 2);
  unsigned*     Bu  = (unsigned*)alloc((size_t)G * TSEQ * NDIM * 4);
  unsigned int* xsb = (unsigned int*)alloc((size_t)G * TSEQ * NDIM * 4);
  float2*       V   = (float2*)alloc((size_t)G * NCHUNK * NDIM * 8);
  float2*       In  = (float2*)alloc((size_t)G * NCHUNK * NDIM * 8);

  const long outs_elems = (long)BATCH * TSEQ * HDIM;
  long out0 = (long)out_size - outs_elems;
  int fs_mode;
  if (out0 >= 16384)     fs_mode = 1;
  else if (out0 >= 8192) fs_mode = 0;
  else { out0 = 0;       fs_mode = -1; }

  float* fs   = (float*)d_out;
  float* outs = (float*)d_out + out0;

  prep_params<<<1, NDIM, 0, stream>>>(nu_log, theta_log, lam_re, lam_im, gam, lamL_re, lamL_im);
  prep_bcat<<<(2 * NDIM * HDIM) / 256, 256, 0, stream>>>(B_re, B_im, gam, Bcat);
  prep_ccat<<<(HDIM * 2 * NDIM) / 256, 256, 0, stream>>>(C_re, C_im, Ccat);

  for (int b0 = 0; b0 < BATCH; b0 += G) {
    const float* ug = u + (size_t)b0 * TSEQ * HDIM;
    int Mloc = G * TSEQ;
    int n4 = Mloc * HDIM / 4;
    conv_u<<<(n4 + 255) / 256, 256, 0, stream>>>((const float4*)ug, ub, n4);

    // GEMM1: Bu[M, 2N] (bf16 packed) = ub[M,512] @ Bcat[1024,512]^T
    int nwg1 = (Mloc / 64) * 16;
    gemmw<512, true><<<nwg1, 64, 0, stream>>>(
        (const unsigned short*)ub, Bcat, Bu, 16, 2 * NDIM, nullptr, nullptr);

    scan_carry<<<(G * NCHUNK * NDIM) / 256, 256, 0, stream>>>(Bu, lam_re, lam_im, V);
    scan_combine<<<(G * NDIM) / 256, 256, 0, stream>>>(
        V, lamL_re, lamL_im, x0r, x0i, b0, In);
    scan_apply<<<(G * NCHUNK * NDIM) / 256, 256, 0, stream>>>(
        Bu, In, lam_re, lam_im, xsb, fs, b0, fs_mode);

    // GEMM2: outs[M,512] = xsb[M,1024] @ Ccat[512,1024]^T + D*u
    int nwg2 = (Mloc / 64) * 8;
    gemmw<1024, false><<<nwg2, 64, 0, stream>>>(
        (const unsigned short*)xsb, Ccat, outs + (size_t)b0 * TSEQ * HDIM,
        8, HDIM, (const unsigned short*)ub, Dv);
  }
}

// Round 13
// 301.512 us; speedup vs baseline: 1.2333x; 1.2333x over previous
//
#include <hip/hip_runtime.h>

// ---------------- Problem constants ----------------
#define BATCH 16
#define TSEQ  4096
#define HDIM  512
#define NDIM  512
#define NCHUNK 64
#define LCHUNK 64   // TSEQ / NCHUNK

using f32x4  = __attribute__((ext_vector_type(4))) float;
using bf16x8 = __attribute__((ext_vector_type(8))) short;

typedef const __attribute__((address_space(1))) void GV;
typedef __attribute__((address_space(3))) void LV;

__device__ __forceinline__ void gload16(const void* g, void* l) {
  __builtin_amdgcn_global_load_lds((GV*)g, (LV*)l, 16, 0, 0);
}
__device__ __forceinline__ unsigned short f2bf(float f) {
  unsigned u = __float_as_uint(f);
  return (unsigned short)((u + 0x7fffu + ((u >> 16) & 1u)) >> 16);
}
__device__ __forceinline__ float bf2f(unsigned short s) {
  return __uint_as_float(((unsigned)s) << 16);
}

// ---------------- Param prep ----------------
__global__ void prep_params(const float* __restrict__ nu_log,
                            const float* __restrict__ theta_log,
                            float* lam_re, float* lam_im, float* gam,
                            float* lamL_re, float* lamL_im) {
  int n = threadIdx.x;
  float en = expf(nu_log[n]);
  float th = expf(theta_log[n]);
  float r  = expf(-en);
  lam_re[n] = r * cosf(th);
  lam_im[n] = r * sinf(th);
  float r2 = expf(-2.f * en);
  gam[n] = sqrtf(fmaxf(1.f - r2, 0.f));
  float rL  = expf(-(float)LCHUNK * en);
  float thL = (float)LCHUNK * th;
  lamL_re[n] = rL * cosf(thL);
  lamL_im[n] = rL * sinf(thL);
}

__global__ void prep_bcat(const float* __restrict__ B_re, const float* __restrict__ B_im,
                          const float* __restrict__ gam, unsigned short* __restrict__ Bcat) {
  int idx = blockIdx.x * 256 + threadIdx.x;
  int h   = idx & (HDIM - 1);
  int row = idx >> 9;
  int n   = row >> 1;
  float g = gam[n];
  float v = (row & 1) ? B_im[n * HDIM + h] : B_re[n * HDIM + h];
  Bcat[idx] = f2bf(g * v);
}

__global__ void prep_ccat(const float* __restrict__ C_re, const float* __restrict__ C_im,
                          unsigned short* __restrict__ Ccat) {
  int idx = blockIdx.x * 256 + threadIdx.x;
  int col = idx & (2 * NDIM - 1);
  int h   = idx >> 10;
  int n   = col >> 1;
  float v = (col & 1) ? -C_im[h * NDIM + n] : C_re[h * NDIM + n];
  Ccat[idx] = f2bf(v);
}

__global__ void conv_u(const float4* __restrict__ u, ushort4* __restrict__ ub, int n4) {
  int idx = blockIdx.x * 256 + threadIdx.x;
  if (idx >= n4) return;
  float4 v = u[idx];
  ushort4 o;
  o.x = f2bf(v.x); o.y = f2bf(v.y); o.z = f2bf(v.z); o.w = f2bf(v.w);
  ub[idx] = o;
}

// ---------------- 256x256 bf16 MFMA GEMM, 4-phase/K-tile (r4, best proven) ----
// C[M,Nd] = A[M,K] @ Bm[Nd,K]^T.  OUTBF: write bf16 (GEMM1->Bu),
// else f32 out + D*u epilogue (GEMM2->outs).  Measured 104us/GEMM (round 5).
template <int K, bool OUTBF>
__global__ __launch_bounds__(512, 2)
void gemm8p(const unsigned short* __restrict__ A,
            const unsigned short* __restrict__ Bm,
            void* __restrict__ Co, int Nb, int Nd,
            const unsigned short* __restrict__ ub,
            const float* __restrict__ Dv) {
  __shared__ char lds[131072];
  const int tid = threadIdx.x;
  const int wid = tid >> 6, lane = tid & 63;
  const int wm = wid >> 2, wn = wid & 3;

  int nwg = gridDim.x;
  int bid = blockIdx.x;
  int wg  = (bid & 7) * (nwg >> 3) + (bid >> 3);
  int bn = wg % Nb, bm = wg / Nb;
  const long rowBase = (long)bm * 256;
  const long colBase = (long)bn * 256;

  const int colE = 8 * ((lane & 7) ^ (lane >> 3));
  const unsigned short* srcA[2][2];
  const unsigned short* srcB[2][2];
#pragma unroll
  for (int a = 0; a < 2; a++)
#pragma unroll
    for (int s = 0; s < 2; s++) {
      long rA = rowBase + a * 128 + s * 64 + wid * 8 + (lane >> 3);
      long rB = colBase + a * 128 + s * 64 + wid * 8 + (lane >> 3);
      srcA[a][s] = A  + rA * K + colE;
      srcB[a][s] = Bm + rB * K + colE;
    }

  f32x4 acc[8][4];
#pragma unroll
  for (int i = 0; i < 8; i++)
#pragma unroll
    for (int j = 0; j < 4; j++) acc[i][j] = (f32x4){0.f, 0.f, 0.f, 0.f};

  const int rowAl = wm * 64 + (lane & 15);
  const int rowBl = wn * 16 + (lane & 15);
  const int kb0   = (lane >> 4) * 16;
  const int sx    = (lane & 7) << 4;

  bf16x8 af[4][2], b0[2][2], b1[2][2];

  auto STAGE = [&](int p, int which, const unsigned short* s0, const unsigned short* s1) {
    char* d = &lds[p * 65536 + which * 16384 + wid * 1024];
    gload16(s0, d);
    gload16(s1, d + 8192);
  };
  auto LDA = [&](int p, int half) {
#pragma unroll
    for (int i = 0; i < 4; i++)
#pragma unroll
      for (int s = 0; s < 2; s++) {
        int off = p * 65536 + half * 16384 +
                  ((((i * 16 + rowAl) << 7) + s * 64 + kb0) ^ sx);
        af[i][s] = *(const bf16x8*)&lds[off];
      }
  };
  auto LDB = [&](bf16x8 bfr[2][2], int p, int bh) {
#pragma unroll
    for (int j = 0; j < 2; j++)
#pragma unroll
      for (int s = 0; s < 2; s++) {
        int off = p * 65536 + 32768 + bh * 16384 +
                  ((((j * 64 + rowBl) << 7) + s * 64 + kb0) ^ sx);
        bfr[j][s] = *(const bf16x8*)&lds[off];
      }
  };
  auto MM = [&](bf16x8 bfr[2][2], int ah, int bh) {
    __builtin_amdgcn_s_setprio(1);
#pragma unroll
    for (int i = 0; i < 4; i++)
#pragma unroll
      for (int j = 0; j < 2; j++)
#pragma unroll
        for (int s = 0; s < 2; s++)
          acc[ah * 4 + i][bh * 2 + j] = __builtin_amdgcn_mfma_f32_16x16x32_bf16(
              af[i][s], bfr[j][s], acc[ah * 4 + i][bh * 2 + j], 0, 0, 0);
    __builtin_amdgcn_s_setprio(0);
  };

#define BAR()   asm volatile("s_barrier" ::: "memory")
#define VM(n)   asm volatile("s_waitcnt vmcnt(" #n ")" ::: "memory")

  const int NT = K / 64;
  STAGE(0, 0, srcA[0][0], srcA[0][1]);
  STAGE(0, 2, srcB[0][0], srcB[0][1]);
  STAGE(0, 3, srcB[1][0], srcB[1][1]);
  STAGE(0, 1, srcA[1][0], srcA[1][1]);
  VM(4);
  BAR();

#pragma unroll 2
  for (int t = 0; t < NT - 1; t++) {
    const int p = t & 1, q = p ^ 1;
    const int ko = (t + 1) * 64;
    LDA(p, 0); LDB(b0, p, 0);
    STAGE(q, 0, srcA[0][0] + ko, srcA[0][1] + ko);
    MM(b0, 0, 0);
    VM(4);
    BAR();
    LDB(b1, p, 1);
    STAGE(q, 2, srcB[0][0] + ko, srcB[0][1] + ko);
    MM(b1, 0, 1);
    VM(4);
    BAR();
    LDA(p, 1);
    STAGE(q, 3, srcB[1][0] + ko, srcB[1][1] + ko);
    MM(b1, 1, 1);
    BAR();
    STAGE(q, 1, srcA[1][0] + ko, srcA[1][1] + ko);
    MM(b0, 1, 0);
    VM(4);
    BAR();
  }
  {
    const int p = (NT - 1) & 1;
    LDA(p, 0); LDB(b0, p, 0);
    MM(b0, 0, 0);
    VM(2);
    BAR();
    LDB(b1, p, 1);
    MM(b1, 0, 1);
    VM(0);
    BAR();
    LDA(p, 1);
    MM(b1, 1, 1);
    MM(b0, 1, 0);
  }
#undef BAR
#undef VM

  const int cc = lane & 15, r4 = (lane >> 4) * 4;
#pragma unroll
  for (int ig = 0; ig < 8; ig++) {
    long row = rowBase + (ig & 3) * 16 + wm * 64 + (ig >> 2) * 128 + r4;
#pragma unroll
    for (int j = 0; j < 4; j++) {
      long col = colBase + j * 64 + wn * 16 + cc;
      if (OUTBF) {
        unsigned short* Cb = (unsigned short*)Co;
#pragma unroll
        for (int r = 0; r < 4; r++)
          Cb[(row + r) * (long)Nd + col] = f2bf(acc[ig][j][r]);
      } else {
        float* Cf = (float*)Co;
        float d = Dv[col];
#pragma unroll
        for (int r = 0; r < 4; r++)
          Cf[(row + r) * (long)Nd + col] =
              acc[ig][j][r] + d * bf2f(ub[(row + r) * (long)Nd + col]);
      }
    }
  }
}

// ---------------- Chunked complex scan, 2 states/thread (uint2/float4) -------
// Layouts of V and In are bit-identical to the scalar version when viewed as
// float2[row*512 + n], so scan_combine is unchanged.
__global__ void scan_carry(const uint2* __restrict__ Bu2,
                           const float* __restrict__ lam_re, const float* __restrict__ lam_im,
                           float4* __restrict__ V4) {
  int idx  = blockIdx.x * 256 + threadIdx.x;  // G*NCHUNK*256
  int n2   = idx & 255;
  int c    = (idx >> 8) & (NCHUNK - 1);
  int bloc = idx >> 14;
  int n    = n2 * 2;
  float lr0 = lam_re[n],     li0 = lam_im[n];
  float lr1 = lam_re[n + 1], li1 = lam_im[n + 1];
  float xr0 = 0.f, xi0 = 0.f, xr1 = 0.f, xi1 = 0.f;
  long base = ((long)bloc * TSEQ + c * LCHUNK) * 256 + n2;  // uint2 units
#pragma unroll 4
  for (int j = 0; j < LCHUNK; j++) {
    uint2 pv = Bu2[base + (long)j * 256];
    float br0 = bf2f((unsigned short)(pv.x & 0xffff));
    float bi0 = bf2f((unsigned short)(pv.x >> 16));
    float br1 = bf2f((unsigned short)(pv.y & 0xffff));
    float bi1 = bf2f((unsigned short)(pv.y >> 16));
    float a0 = lr0 * xr0 - li0 * xi0 + br0;
    float b0 = lr0 * xi0 + li0 * xr0 + bi0;
    float a1 = lr1 * xr1 - li1 * xi1 + br1;
    float b1 = lr1 * xi1 + li1 * xr1 + bi1;
    xr0 = a0; xi0 = b0; xr1 = a1; xi1 = b1;
  }
  V4[((long)bloc * NCHUNK + c) * 256 + n2] = make_float4(xr0, xi0, xr1, xi1);
}

__global__ void scan_combine(const float2* __restrict__ V,
                             const float* __restrict__ lamL_re, const float* __restrict__ lamL_im,
                             const float* __restrict__ x0r, const float* __restrict__ x0i,
                             int b0, float2* __restrict__ In) {
  int idx  = blockIdx.x * 256 + threadIdx.x;  // G*512
  int n    = idx & (NDIM - 1);
  int bloc = idx >> 9;
  int b    = b0 + bloc;
  float lr = lamL_re[n], li = lamL_im[n];
  float sr = x0r[b * NDIM + n], si = x0i[b * NDIM + n];
  long base = (long)bloc * NCHUNK * NDIM + n;
  for (int c = 0; c < NCHUNK; c++) {
    In[base + c * NDIM] = make_float2(sr, si);
    float2 v = V[base + c * NDIM];
    float nr = lr * sr - li * si + v.x;
    float ni = lr * si + li * sr + v.y;
    sr = nr; si = ni;
  }
}

__global__ void scan_apply(const uint2* __restrict__ Bu2, const float4* __restrict__ In4,
                           const float* __restrict__ lam_re, const float* __restrict__ lam_im,
                           uint2* __restrict__ xsb2, float* __restrict__ fs,
                           int b0, int fs_mode) {
  int idx  = blockIdx.x * 256 + threadIdx.x;  // G*NCHUNK*256
  int n2   = idx & 255;
  int c    = (idx >> 8) & (NCHUNK - 1);
  int bloc = idx >> 14;
  int n    = n2 * 2;
  float lr0 = lam_re[n],     li0 = lam_im[n];
  float lr1 = lam_re[n + 1], li1 = lam_im[n + 1];
  float4 s = In4[((long)bloc * NCHUNK + c) * 256 + n2];
  float xr0 = s.x, xi0 = s.y, xr1 = s.z, xi1 = s.w;
  long base = ((long)bloc * TSEQ + c * LCHUNK) * 256 + n2;  // uint2 units
#pragma unroll 4
  for (int j = 0; j < LCHUNK; j++) {
    uint2 pv = Bu2[base + (long)j * 256];
    float br0 = bf2f((unsigned short)(pv.x & 0xffff));
    float bi0 = bf2f((unsigned short)(pv.x >> 16));
    float br1 = bf2f((unsigned short)(pv.y & 0xffff));
    float bi1 = bf2f((unsigned short)(pv.y >> 16));
    float a0 = lr0 * xr0 - li0 * xi0 + br0;
    float b0 = lr0 * xi0 + li0 * xr0 + bi0;
    float a1 = lr1 * xr1 - li1 * xi1 + br1;
    float b1 = lr1 * xi1 + li1 * xr1 + bi1;
    xr0 = a0; xi0 = b0; xr1 = a1; xi1 = b1;
    uint2 o;
    o.x = (unsigned)f2bf(xr0) | ((unsigned)f2bf(xi0) << 16);
    o.y = (unsigned)f2bf(xr1) | ((unsigned)f2bf(xi1) << 16);
    xsb2[base + (long)j * 256] = o;
  }
  if (c == NCHUNK - 1 && fs_mode >= 0) {
    int b = b0 + bloc;
    if (fs_mode == 1) {
      fs[(size_t)(b * NDIM + n) * 2]     = xr0;
      fs[(size_t)(b * NDIM + n) * 2 + 1] = xi0;
      fs[(size_t)(b * NDIM + n) * 2 + 2] = xr1;
      fs[(size_t)(b * NDIM + n) * 2 + 3] = xi1;
    } else {
      fs[(size_t)(b * NDIM + n)]     = xr0;
      fs[(size_t)(b * NDIM + n) + 1] = xr1;
    }
  }
}

// ---------------- Host launch ----------------
extern "C" void kernel_launch(void* const* d_in, const int* in_sizes, int n_in,
                              void* d_out, int out_size, void* d_ws, size_t ws_size,
                              hipStream_t stream) {
  const float* x0r       = (const float*)d_in[0];
  const float* x0i       = (const float*)d_in[1];
  const float* u         = (const float*)d_in[2];
  const float* nu_log    = (const float*)d_in[3];
  const float* theta_log = (const float*)d_in[4];
  const float* B_re      = (const float*)d_in[5];
  const float* B_im      = (const float*)d_in[6];
  const float* C_re      = (const float*)d_in[7];
  const float* C_im      = (const float*)d_in[8];
  const float* Dv        = (const float*)d_in[9];

  char* ws = (char*)d_ws;
  size_t off = 0;
  auto alloc = [&](size_t bytes) {
    char* p = ws + off;
    off = (off + bytes + 255) & ~(size_t)255;
    return p;
  };

  float* lam_re  = (float*)alloc(NDIM * 4);
  float* lam_im  = (float*)alloc(NDIM * 4);
  float* gam     = (float*)alloc(NDIM * 4);
  float* lamL_re = (float*)alloc(NDIM * 4);
  float* lamL_im = (float*)alloc(NDIM * 4);
  unsigned short* Bcat = (unsigned short*)alloc((size_t)2 * NDIM * HDIM * 2);
  unsigned short* Ccat = (unsigned short*)alloc((size_t)HDIM * 2 * NDIM * 2);

  const size_t per_batch =
      (size_t)TSEQ * HDIM * 2 +       // u bf16
      (size_t)TSEQ * NDIM * 4 +       // Bu packed bf16 (re|im)
      (size_t)TSEQ * NDIM * 4 +       // xs packed bf16
      (size_t)2 * NCHUNK * NDIM * 8 + // V, In
      4096;
  int G = 16;
  while (G > 1 && off + (size_t)G * per_batch > ws_size) G >>= 1;

  ushort4*      ub  = (ushort4*)alloc((size_t)G * TSEQ * HDIM * 2);
  unsigned*     Bu  = (unsigned*)alloc((size_t)G * TSEQ * NDIM * 4);
  unsigned int* xsb = (unsigned int*)alloc((size_t)G * TSEQ * NDIM * 4);
  float4*       V   = (float4*)alloc((size_t)G * NCHUNK * NDIM * 8);
  float4*       In  = (float4*)alloc((size_t)G * NCHUNK * NDIM * 8);

  const long outs_elems = (long)BATCH * TSEQ * HDIM;
  long out0 = (long)out_size - outs_elems;
  int fs_mode;
  if (out0 >= 16384)     fs_mode = 1;
  else if (out0 >= 8192) fs_mode = 0;
  else { out0 = 0;       fs_mode = -1; }

  float* fs   = (float*)d_out;
  float* outs = (float*)d_out + out0;

  prep_params<<<1, NDIM, 0, stream>>>(nu_log, theta_log, lam_re, lam_im, gam, lamL_re, lamL_im);
  prep_bcat<<<(2 * NDIM * HDIM) / 256, 256, 0, stream>>>(B_re, B_im, gam, Bcat);
  prep_ccat<<<(HDIM * 2 * NDIM) / 256, 256, 0, stream>>>(C_re, C_im, Ccat);

  for (int b0 = 0; b0 < BATCH; b0 += G) {
    const float* ug = u + (size_t)b0 * TSEQ * HDIM;
    int Mloc = G * TSEQ;
    int n4 = Mloc * HDIM / 4;
    conv_u<<<(n4 + 255) / 256, 256, 0, stream>>>((const float4*)ug, ub, n4);

    // GEMM1: Bu[M, 2N] (bf16 packed) = ub[M,512] @ Bcat[1024,512]^T
    int nwg1 = (Mloc / 256) * 4;
    gemm8p<512, true><<<nwg1, 512, 0, stream>>>(
        (const unsigned short*)ub, Bcat, Bu, 4, 2 * NDIM, nullptr, nullptr);

    scan_carry<<<(G * NCHUNK * 256) / 256, 256, 0, stream>>>(
        (const uint2*)Bu, lam_re, lam_im, V);
    scan_combine<<<(G * NDIM) / 256, 256, 0, stream>>>(
        (const float2*)V, lamL_re, lamL_im, x0r, x0i, b0, (float2*)In);
    scan_apply<<<(G * NCHUNK * 256) / 256, 256, 0, stream>>>(
        (const uint2*)Bu, (const float4*)In, lam_re, lam_im,
        (uint2*)xsb, fs, b0, fs_mode);

    // GEMM2: outs[M,512] = xsb[M,1024] @ Ccat[512,1024]^T + D*u
    int nwg2 = (Mloc / 256) * 2;
    gemm8p<1024, false><<<nwg2, 512, 0, stream>>>(
        (const unsigned short*)xsb, Ccat, outs + (size_t)b0 * TSEQ * HDIM,
        2, HDIM, (const unsigned short*)ub, Dv);
  }
}